// Round 1
// baseline (125.276 us; speedup 1.0000x reference)
//
#include <hip/hip_runtime.h>
#include <math.h>

// Planar normalizing flow, B=524288 rows, D=64 features, F=32 flows.
// One thread per row; z[64] lives in VGPRs; flow params are precomputed
// into workspace and read via wave-uniform (scalar) loads inside the f-loop.

#define NF_D 64
#define NF_F 32

// --- Step 1: precompute u_hat[F][D] and wuh[F] = w . u_hat ---------------
__global__ void nf_precompute(const float* __restrict__ us,
                              const float* __restrict__ ws,
                              float* __restrict__ uhat,
                              float* __restrict__ wuh) {
  int f = threadIdx.x;
  if (f >= NF_F) return;
  const float* u = us + f * NF_D;
  const float* w = ws + f * NF_D;
  float wu = 0.f, n2 = 0.f;
  for (int d = 0; d < NF_D; ++d) {
    wu = fmaf(u[d], w[d], wu);
    n2 = fmaf(w[d], w[d], n2);
  }
  // softplus(wu) = max(wu,0) + log1p(exp(-|wu|))
  float sp = fmaxf(wu, 0.f) + log1pf(expf(-fabsf(wu)));
  float coef = (sp - 1.f - wu) / sqrtf(n2);   // u_hat = u + coef * w
  for (int d = 0; d < NF_D; ++d)
    uhat[f * NF_D + d] = fmaf(coef, w[d], u[d]);
  wuh[f] = fmaf(coef, n2, wu);                // w . u_hat
}

// tanh(x) = 1 - 2/(e^{2x}+1); exp2/rcp hardware approx.
// Saturates correctly: x->+inf: e=inf, rcp=0 -> 1; x->-inf: e=0 -> -1.
__device__ __forceinline__ float fast_tanh(float x) {
  float e = __builtin_amdgcn_exp2f(x * 2.885390081777927f); // 2*log2(e)
  return 1.f - 2.f * __builtin_amdgcn_rcpf(e + 1.f);
}

// --- Step 2: main flow, one thread per row -------------------------------
__global__ __launch_bounds__(256) void nf_main(
    const float* __restrict__ x,
    const float* __restrict__ ws,
    const float* __restrict__ bs,
    const float* __restrict__ uhat,
    const float* __restrict__ wuh,
    float* __restrict__ out_z,
    float* __restrict__ out_ld,
    int B) {
  int row = blockIdx.x * blockDim.x + threadIdx.x;
  if (row >= B) return;

  float z[NF_D];
  const float4* xv = reinterpret_cast<const float4*>(x + (size_t)row * NF_D);
  #pragma unroll
  for (int k = 0; k < NF_D / 4; ++k) {
    float4 v = xv[k];
    z[4 * k + 0] = v.x; z[4 * k + 1] = v.y;
    z[4 * k + 2] = v.z; z[4 * k + 3] = v.w;
  }

  float sld = 0.f;
  for (int f = 0; f < NF_F; ++f) {       // f is wave-uniform -> scalar loads
    const float* __restrict__ wf = ws + f * NF_D;
    const float* __restrict__ uf = uhat + f * NF_D;
    // 4 accumulators to break the FMA dependency chain
    float a0 = 0.f, a1 = 0.f, a2 = 0.f, a3 = 0.f;
    #pragma unroll
    for (int d = 0; d < NF_D; d += 4) {
      a0 = fmaf(z[d + 0], wf[d + 0], a0);
      a1 = fmaf(z[d + 1], wf[d + 1], a1);
      a2 = fmaf(z[d + 2], wf[d + 2], a2);
      a3 = fmaf(z[d + 3], wf[d + 3], a3);
    }
    float lin = ((a0 + a1) + (a2 + a3)) + bs[f];
    float h = fast_tanh(lin);
    #pragma unroll
    for (int d = 0; d < NF_D; ++d)
      z[d] = fmaf(uf[d], h, z[d]);
    float hp = fmaf(-h, h, 1.f);               // 1 - h^2
    float t  = fmaf(hp, wuh[f], 1.f);          // 1 + h' * (w.u_hat)
    sld += __builtin_amdgcn_logf(fabsf(t)) * 0.6931471805599453f;
  }

  float4* ov = reinterpret_cast<float4*>(out_z + (size_t)row * NF_D);
  #pragma unroll
  for (int k = 0; k < NF_D / 4; ++k)
    ov[k] = make_float4(z[4 * k + 0], z[4 * k + 1], z[4 * k + 2], z[4 * k + 3]);
  out_ld[row] = sld;
}

extern "C" void kernel_launch(void* const* d_in, const int* in_sizes, int n_in,
                              void* d_out, int out_size, void* d_ws, size_t ws_size,
                              hipStream_t stream) {
  const float* x    = (const float*)d_in[0];
  const float* us   = (const float*)d_in[1];
  const float* ws_p = (const float*)d_in[2];
  const float* bs   = (const float*)d_in[3];
  const int B = in_sizes[0] / NF_D;

  float* uhat = (float*)d_ws;            // F*D floats
  float* wuh  = uhat + NF_F * NF_D;      // F floats
  float* out  = (float*)d_out;           // z [B*D] then sum_log_det [B]

  nf_precompute<<<1, 64, 0, stream>>>(us, ws_p, uhat, wuh);
  const int block = 256;
  const int grid = (B + block - 1) / block;
  nf_main<<<grid, block, 0, stream>>>(x, ws_p, bs, uhat, wuh,
                                      out, out + (size_t)B * NF_D, B);
}